// Round 6
// baseline (45.868 us; speedup 1.0000x reference)
//
#include <hip/hip_runtime.h>

#define T_LEN     8000
#define NGRAN     2000          // 16B granules per row
#define NGRAN_PAD 2048
#define F_BANDS   128
#define CHUNK     16            // elements per thread
#define BLOCK     512           // 500 active threads cover 8000
#define NWAVE     (BLOCK / 64)
#define GPW       256           // granules per wave (64 lanes * 4 granules)
#define RPB       8             // rows per block (software-pipelined)
#define EPS_F     1e-6f
#define LOG2E     1.44269504088896340736f

typedef float floatx4 __attribute__((ext_vector_type(4)));

// raw hardware transcendentals (base-2), no libm header conflicts
__device__ __forceinline__ float hexp2(float v) { return __builtin_amdgcn_exp2f(v); }
__device__ __forceinline__ float hlog2(float v) { return __builtin_amdgcn_logf(v); }
__device__ __forceinline__ float hexp(float v)  { return hexp2(v * LOG2E); }

// XOR involution on 16B granule index; permutes granules only WITHIN a 128B
// line (bits 0-2 xor bits 3-5), so pre-swizzled global reads stay coalesced.
__device__ __forceinline__ int swz(int g) { return g ^ ((g >> 3) & 7); }

typedef __attribute__((address_space(1))) const unsigned int gu32_t;
typedef __attribute__((address_space(3))) unsigned int lu32_t;

__global__ __launch_bounds__(BLOCK, 4) void pcen_kernel(
    const float* __restrict__ x,
    const float* __restrict__ log_s,
    const float* __restrict__ log_alpha,
    const float* __restrict__ log_delta,
    const float* __restrict__ log_r,
    float* __restrict__ out)
{
    __shared__ float lds[2][NGRAN_PAD * 4];   // 2 x 32 KiB double buffer
    __shared__ float wtot[2][NWAVE];          // parity-double-buffered

    const int tid  = threadIdx.x;
    const int lane = tid & 63;
    const int wv   = tid >> 6;
    const int row0 = blockIdx.x * RPB;
    const int fb0  = row0 & (F_BANDS - 1);    // multiple of 8, no wrap over +7

    // ---- hoist ALL per-row params to registers (keeps vmcnt counting exact) ----
    float sv[RPB], av[RPB], alv[RPB], dev[RPB], rv[RPB], drv[RPB];
    #pragma unroll
    for (int j = 0; j < RPB; ++j) {
        sv[j]  = hexp(log_s[fb0 + j]);
        av[j]  = 1.0f - sv[j];
        alv[j] = hexp(log_alpha[fb0 + j]);
        dev[j] = hexp(log_delta[fb0 + j]);
        rv[j]  = hexp(log_r[fb0 + j]);
        drv[j] = hexp2(rv[j] * hlog2(dev[j]));     // delta^r
    }

    // wave-local staging of row j into buffer `buf`: linear LDS dest,
    // pre-swizzled global source. Exactly 4 vmem ops per wave.
    auto stage = [&](int buf, int j) {
        const float* xrow = x + (size_t)(row0 + j) * T_LEN;
        #pragma unroll
        for (int c = 0; c < 4; ++c) {
            const int hbase = wv * GPW + c * 64;   // wave-uniform granule base
            const int h     = hbase + lane;
            int hs = swz(h);
            if (h >= NGRAN) hs = 0;
            __builtin_amdgcn_global_load_lds((gu32_t*)(xrow + 4 * hs),
                                             (lu32_t*)&lds[buf][4 * hbase], 16, 0, 0);
        }
    };

    stage(0, 0);                                   // prologue

    const bool active = tid < (T_LEN / CHUNK);     // tid < 500

    // vmem issue order per wave: P,L0 | L1 [w4] C0 S0 | L2 [w8] C1 S1 | ...
    // | L7 [w8] C6 S6 | [w4] C7 S7.  vmcnt retires in issue order (gfx9
    // lineage), so vmcnt(8) = {S_{j-1}, L_{j+1}} may stay in flight while
    // L_j is guaranteed complete — counted waits, never drain to 0 (T4).
    #pragma unroll
    for (int j = 0; j < RPB; ++j) {
        const int cur = j & 1;
        if (j + 1 < RPB) stage(cur ^ 1, j + 1);    // issue next row's loads first

        if (j == 0 || j == RPB - 1) {
            asm volatile("s_waitcnt vmcnt(4)" ::: "memory");
        } else {
            asm volatile("s_waitcnt vmcnt(8)" ::: "memory");
        }
        __builtin_amdgcn_sched_barrier(0);

        const float s = sv[j], a = av[j], alpha = alv[j];
        const float delta = dev[j], r = rv[j], dr = drv[j];

        // ---- read this thread's 16 contiguous elements from LDS (swizzled) ----
        floatx4 v[CHUNK / 4];
        if (active) {
            #pragma unroll
            for (int m = 0; m < CHUNK / 4; ++m)
                v[m] = *reinterpret_cast<const floatx4*>(&lds[cur][4 * swz(tid * 4 + m)]);
        } else {
            #pragma unroll
            for (int m = 0; m < CHUNK / 4; ++m) v[m] = (floatx4)(0.0f);
        }
        float* xv = reinterpret_cast<float*>(v);

        float A = a;
        #pragma unroll
        for (int i = 0; i < 4; ++i) A *= A;        // a^16

        // pass 1: local scan, zero-seeded (thread 0 seeds with x[0])
        float fB = (tid == 0) ? xv[0] : 0.0f;
        #pragma unroll
        for (int k = 0; k < CHUNK; ++k) fB = fmaf(a, fB, s * xv[k]);

        // wave-inclusive scan over chunk states with coefficient A
        float val = fB;
        float Ad  = A;
        #pragma unroll
        for (int d = 1; d < 64; d <<= 1) {
            float up = __shfl_up(val, d, 64);
            if (lane >= d) val = fmaf(Ad, up, val);
            Ad *= Ad;
        }
        const float Aw = Ad;                       // A^64, per-wave decay

        // cross-wave combine: ONE barrier per row, parity-buffered wtot
        if (lane == 63) wtot[cur][wv] = val;
        __syncthreads();
        float C = 0.0f;
        for (int u = 0; u < wv; ++u) C = fmaf(Aw, C, wtot[cur][u]);

        float E = __shfl_up(val, 1, 64);
        if (lane == 0) E = 0.0f;

        float Al = 1.0f, p = A;                    // A^lane, repeated squaring
        #pragma unroll
        for (int b = 0; b < 6; ++b) {
            if (lane & (1 << b)) Al *= p;
            p *= p;
        }

        float carry = fmaf(Al, C, E);              // state entering this chunk
        if (tid == 0) carry = xv[0];

        // pass 2: re-scan + fused PCEN, results back to LDS (wave-local)
        if (active) {
            float fcur = carry;
            #pragma unroll
            for (int k = 0; k < CHUNK; ++k) {
                float xk = xv[k];
                fcur = fmaf(a, fcur, s * xk);
                float u2 = xk * hexp2(-alpha * hlog2(EPS_F + fcur));
                xv[k]    = hexp2(r * hlog2(u2 + delta)) - dr;
            }
            #pragma unroll
            for (int m = 0; m < CHUNK / 4; ++m)
                *reinterpret_cast<floatx4*>(&lds[cur][4 * swz(tid * 4 + m)]) = v[m];
        }
        // no barrier: store sweep reads only THIS wave's granule range

        // wave-local coalesced nt store sweep: exactly 4 vmem stores per wave
        float* orow = out + (size_t)(row0 + j) * T_LEN;
        #pragma unroll
        for (int c = 0; c < 4; ++c) {
            const int h = wv * GPW + c * 64 + lane;
            if (h < NGRAN) {
                floatx4 val4 = *reinterpret_cast<const floatx4*>(&lds[cur][4 * swz(h)]);
                __builtin_nontemporal_store(val4, reinterpret_cast<floatx4*>(&orow[4 * h]));
            }
        }
    }
}

extern "C" void kernel_launch(void* const* d_in, const int* in_sizes, int n_in,
                              void* d_out, int out_size, void* d_ws, size_t ws_size,
                              hipStream_t stream) {
    const float* x  = (const float*)d_in[0];
    const float* ls = (const float*)d_in[1];
    const float* la = (const float*)d_in[2];
    const float* ld = (const float*)d_in[3];
    const float* lr = (const float*)d_in[4];
    float* out = (float*)d_out;

    const int rows = out_size / T_LEN;       // 4096
    pcen_kernel<<<rows / RPB, BLOCK, 0, stream>>>(x, ls, la, ld, lr, out);
}

// Round 7
// 45.189 us; speedup vs baseline: 1.0150x; 1.0150x over previous
//
#include <hip/hip_runtime.h>

#define T_LEN     8000
#define NGRAN     2000          // 16B granules per row
#define NGRAN_PAD 2048
#define F_BANDS   128
#define CHUNK     16            // elements per thread
#define BLOCK     512           // 500 active threads cover 8000
#define NWAVE     (BLOCK / 64)
#define GPW       256           // granules per wave (64 lanes * 4 granules)
#define EPS_F     1e-6f
#define LOG2E     1.44269504088896340736f

typedef float  floatx4 __attribute__((ext_vector_type(4)));

// raw hardware transcendentals (base-2), no libm header conflicts
__device__ __forceinline__ float hexp2(float v) { return __builtin_amdgcn_exp2f(v); }
__device__ __forceinline__ float hlog2(float v) { return __builtin_amdgcn_logf(v); }
__device__ __forceinline__ float hexp(float v)  { return hexp2(v * LOG2E); }

// XOR involution on 16B granule index; permutes granules only WITHIN a 128B
// line (bits 0-2 xor bits 3-5), so pre-swizzled global reads stay coalesced.
__device__ __forceinline__ int swz(int g) { return g ^ ((g >> 3) & 7); }

typedef __attribute__((address_space(1))) const unsigned int gu32_t;
typedef __attribute__((address_space(3))) unsigned int lu32_t;

__global__ __launch_bounds__(BLOCK) void pcen_kernel(
    const float* __restrict__ x,
    const float* __restrict__ log_s,
    const float* __restrict__ log_alpha,
    const float* __restrict__ log_delta,
    const float* __restrict__ log_r,
    float* __restrict__ out)
{
    __shared__ float lds[NGRAN_PAD * 4];    // 32 KiB data (swizzled granules)
    __shared__ float wtot[NWAVE];

    const int row  = blockIdx.x;            // b*F + f  (C==1)
    const int fb   = row & (F_BANDS - 1);
    const int tid  = threadIdx.x;
    const int lane = tid & 63;
    const int wv   = tid >> 6;

    const float* xrow = x   + (size_t)row * T_LEN;
    float*       orow = out + (size_t)row * T_LEN;

    // ---- wave-local staging: each wave stages ITS OWN granule range ----
    // linear LDS dest (wave-uniform base + lane*16), pre-swizzled source.
    #pragma unroll
    for (int c = 0; c < 4; ++c) {
        const int hbase = wv * GPW + c * 64;    // wave-uniform granule base
        const int h     = hbase + lane;
        int hs = swz(h);
        if (h >= NGRAN) hs = 0;                 // pad granules: any valid addr
        __builtin_amdgcn_global_load_lds((gu32_t*)(xrow + 4 * hs),
                                         (lu32_t*)&lds[4 * hbase], 16, 0, 0);
    }

    // per-band scalars (uniform within block) — overlaps with load latency
    const float s     = hexp(log_s[fb]);
    const float a     = 1.0f - s;
    const float alpha = hexp(log_alpha[fb]);
    const float delta = hexp(log_delta[fb]);
    const float r     = hexp(log_r[fb]);
    const float dr    = hexp2(r * hlog2(delta));       // delta^r

    // wait for THIS wave's staging loads only (no block barrier)
    asm volatile("s_waitcnt vmcnt(0)" ::: "memory");
    __builtin_amdgcn_sched_barrier(0);

    const bool active = tid < (T_LEN / CHUNK);  // tid < 500

    // ---- read this thread's 16 contiguous elements from LDS (swizzled) ----
    floatx4 v[CHUNK / 4];
    if (active) {
        #pragma unroll
        for (int m = 0; m < CHUNK / 4; ++m)
            v[m] = *reinterpret_cast<const floatx4*>(&lds[4 * swz(tid * 4 + m)]);
    } else {
        #pragma unroll
        for (int m = 0; m < CHUNK / 4; ++m)
            v[m] = (floatx4)(0.0f);
    }
    float* xv = reinterpret_cast<float*>(v);

    // A = a^CHUNK (per-chunk decay)
    float A = a;
    #pragma unroll
    for (int i = 0; i < 4; ++i) A *= A;     // a^16

    // ---- pass 1: local scan, zero-seeded (thread 0 seeds with x[0]) ----
    float fB = (tid == 0) ? xv[0] : 0.0f;
    #pragma unroll
    for (int k = 0; k < CHUNK; ++k) fB = fmaf(a, fB, s * xv[k]);

    // ---- wave-inclusive scan over chunk states with coefficient A ----
    float val = fB;
    float Ad  = A;
    #pragma unroll
    for (int d = 1; d < 64; d <<= 1) {
        float up = __shfl_up(val, d, 64);
        if (lane >= d) val = fmaf(Ad, up, val);
        Ad *= Ad;                            // A^(2d)
    }
    const float Aw = Ad;                     // A^64, per-wave decay

    // ---- cross-wave combine: the ONLY block-wide barrier ----
    if (lane == 63) wtot[wv] = val;
    __syncthreads();
    float C = 0.0f;                          // state entering this wave
    for (int u = 0; u < wv; ++u) C = fmaf(Aw, C, wtot[u]);

    // exclusive within-wave prefix
    float E = __shfl_up(val, 1, 64);
    if (lane == 0) E = 0.0f;

    // A^lane via branchless repeated squaring
    float Al = 1.0f, p = A;
    #pragma unroll
    for (int b = 0; b < 6; ++b) {
        if (lane & (1 << b)) Al *= p;
        p *= p;
    }

    float carry = fmaf(Al, C, E);            // state entering this chunk
    if (tid == 0) carry = xv[0];             // recurrence then yields f0 = x[0]

    // ---- pass 2: re-scan + fused PCEN, results back to LDS (wave-local) ----
    if (active) {
        float fcur = carry;
        #pragma unroll
        for (int k = 0; k < CHUNK; ++k) {
            float xk = xv[k];
            fcur = fmaf(a, fcur, s * xk);                        // smoother
            float u = xk * hexp2(-alpha * hlog2(EPS_F + fcur));
            xv[k]   = hexp2(r * hlog2(u + delta)) - dr;
        }
        #pragma unroll
        for (int m = 0; m < CHUNK / 4; ++m)
            *reinterpret_cast<floatx4*>(&lds[4 * swz(tid * 4 + m)]) = v[m];
    }
    // no barrier: store sweep below reads only THIS wave's granule range,
    // written by this wave's own threads (lgkmcnt dependency, compiler-tracked)

    // ---- wave-local coalesced store sweep (non-temporal: don't evict L3) ----
    #pragma unroll
    for (int c = 0; c < 4; ++c) {
        const int h = wv * GPW + c * 64 + lane;
        if (h < NGRAN) {
            floatx4 val4 = *reinterpret_cast<const floatx4*>(&lds[4 * swz(h)]);
            __builtin_nontemporal_store(val4, reinterpret_cast<floatx4*>(&orow[4 * h]));
        }
    }
}

extern "C" void kernel_launch(void* const* d_in, const int* in_sizes, int n_in,
                              void* d_out, int out_size, void* d_ws, size_t ws_size,
                              hipStream_t stream) {
    const float* x  = (const float*)d_in[0];
    const float* ls = (const float*)d_in[1];
    const float* la = (const float*)d_in[2];
    const float* ld = (const float*)d_in[3];
    const float* lr = (const float*)d_in[4];
    float* out = (float*)d_out;

    const int rows = out_size / T_LEN;       // 32*1*128 = 4096
    pcen_kernel<<<rows, BLOCK, 0, stream>>>(x, ls, la, ld, lr, out);
}